// Round 8
// baseline (296.545 us; speedup 1.0000x reference)
//
#include <hip/hip_runtime.h>
#include <hip/hip_bf16.h>

typedef __attribute__((ext_vector_type(4))) float f32x4;
typedef __attribute__((ext_vector_type(8))) short bf16x8;
typedef __attribute__((ext_vector_type(4))) short bf16x4v;

#define M_DIM 8192
#define N_DIM 4096
#define K_DIM 4096
#define NX (M_DIM * K_DIM)
#define NW (N_DIM * K_DIM)

#define BM 256
#define BN 256
#define BK 64
#define NKT (K_DIM / BK)   /* 64 */
#define THREADS 512

#define GLOAD_LDS16(g, l)                                                        \
  __builtin_amdgcn_global_load_lds(                                              \
      (const __attribute__((address_space(1))) void*)(g),                        \
      (__attribute__((address_space(3))) void*)(l), 16, 0, 0)

// ---------------------------------------------------------------------------
// Pass 1: fp32 -> bf16 conversion of x and W into workspace.
// ---------------------------------------------------------------------------
__global__ __launch_bounds__(256) void convert_bf16(const float* __restrict__ x,
                                                    const float* __restrict__ w,
                                                    short* __restrict__ ws) {
  const long stride = (long)gridDim.x * blockDim.x;
  const long total8 = ((long)NX + NW) / 8;
  for (long i = blockIdx.x * (long)blockDim.x + threadIdx.x; i < total8; i += stride) {
    const long base = i * 8;
    const float* src = (base < NX) ? (x + base) : (w + (base - NX));
    short* dst = ws + base;
    f32x4 a = *(const f32x4*)src;
    f32x4 b = *(const f32x4*)(src + 4);
    bf16x8 o;
    o[0] = (short)__bfloat16_as_ushort(__float2bfloat16(a[0]));
    o[1] = (short)__bfloat16_as_ushort(__float2bfloat16(a[1]));
    o[2] = (short)__bfloat16_as_ushort(__float2bfloat16(a[2]));
    o[3] = (short)__bfloat16_as_ushort(__float2bfloat16(a[3]));
    o[4] = (short)__bfloat16_as_ushort(__float2bfloat16(b[0]));
    o[5] = (short)__bfloat16_as_ushort(__float2bfloat16(b[1]));
    o[6] = (short)__bfloat16_as_ushort(__float2bfloat16(b[2]));
    o[7] = (short)__bfloat16_as_ushort(__float2bfloat16(b[3]));
    *(bf16x8*)dst = o;
  }
}

// ---------------------------------------------------------------------------
// Pass 2: 256x256 bf16 GEMM, BK=64, 8 waves (2M x 4N), double-buffered LDS.
// 4 phases per K-tile, one trailing barrier each, NO explicit lgkm drains
// (compiler emits fine-grained lgkmcnt).  ALL staging for tile t+2 issues at
// t.ph3 (the earliest point buf[t&1] is fully read), giving every
// global_load_lds a full K-tile (~4 phases) of flight before its vmcnt(8)
// gate at t+1.ph3 -- covers HBM-miss latency, not just L2.
// XOR slot swizzle; XCD-aware block swizzle; setprio.
// Y = relu(X @ W^T + b)
//
// LDS per buffer (64 KiB): A rows 0-255 at [0,32KB) (half0 rows 0-127,
// half1 rows 128-255), B likewise at [32KB,64KB). Rows 128 B, 8 slots of
// 16 B, phys slot = logical ^ (row&7).
//
// Race audit:
//  - reads of buf[t&1] (tile t) all occur in t.ph0-ph2; ph2's trailing
//    barrier seals them; ph3's 8 stores into buf[t&1] follow it.
//  - vmcnt(8) at t.ph3: outstanding = t+1's 8 (issued t-1.ph3) + t+2's 8
//    (just issued); waits the older 8 -> tile t+1 resident; trailing
//    barrier publishes before any t+1.ph0 read.  "memory" clobber stops
//    ds_read hoisting above the gate.
// ---------------------------------------------------------------------------
__global__ __launch_bounds__(THREADS, 2) void gemm256_bf16(
    const short* __restrict__ Abf,   /* [M][K] bf16 */
    const short* __restrict__ Bbf,   /* [N][K] bf16 */
    const float* __restrict__ bias,
    float* __restrict__ Y) {
  __shared__ short lds[2 * 32768];   /* 128 KiB */
  char* const ldsb = (char*)lds;

  const int tid  = threadIdx.x;
  const int lane = tid & 63;
  const int wave = tid >> 6;       // 0..7
  const int wm   = wave >> 2;      // 0..1  (M half)
  const int wn   = wave & 3;       // 0..3  (N quarter)

  // XCD-aware bijective swizzle: 512 wgs = 8 XCDs x 64.
  const int lin = blockIdx.x + blockIdx.y * (N_DIM / BN);   // gridDim.x = 16
  const int swz = (lin & 7) * 64 + (lin >> 3);
  const int bx = swz & 15;         // N tile
  const int by = swz >> 4;         // M tile
  const long rowA0 = (long)by * BM;
  const long rowB0 = (long)bx * BN;

  // staging: one GLOAD issue = 512 thr x 16 B = 64 rows x 128 B.
  // LDS linear row = wave*8 + (lane>>3) within a 64-row group; phys slot =
  // lane&7; source col chunk = phys ^ (row&7) (inverse swizzle).
  const int sg_col = (((lane & 7) ^ ((lane >> 3) & 7)) << 3);
  const int s_row  = wave * 8 + (lane >> 3);
  const int voff = s_row * K_DIM + sg_col;

  const short* uA = Abf + rowA0 * (long)K_DIM;
  const short* uB = Bbf + rowB0 * (long)K_DIM;

  // fragment-read per-lane byte offsets: row = frag*16 + (lane&15),
  // phys slot = kslot ^ (row&7) = kslot ^ (lane&7).
  const int offk0 = (lane & 15) * 128 + ((((lane >> 4)) ^ (lane & 7)) << 4);
  const int offk1 = (lane & 15) * 128 + (((4 + (lane >> 4)) ^ (lane & 7)) << 4);

// stage one half-tile (2 gloads). HALF: 0 = A rows 0-127, 1 = A rows 128-255,
// 2 = B rows 0-127, 3 = B rows 128-255.
#define STAGE_HALF(BOFF_, HALF_, TT) do {                                        \
    const short* u_ = ((HALF_) < 2 ? uA : uB) +                                  \
                      (long)(((HALF_) & 1) * 128) * K_DIM + (long)(TT) * BK;     \
    char* l_ = ldsb + (BOFF_) + ((HALF_) < 2 ? 0 : 32768) +                      \
               ((HALF_) & 1) * 16384 + wave * 1024;                              \
    GLOAD_LDS16(u_ + voff, l_);                                                  \
    GLOAD_LDS16(u_ + 64 * K_DIM + voff, l_ + 8192);                              \
  } while (0)

#define PH_READ_A(DST, BOFF_, MADD) do {                                         \
    const char* pa_ = ldsb + (BOFF_) + wm * 16384 + (MADD);                      \
    _Pragma("unroll")                                                            \
    for (int m_ = 0; m_ < 4; ++m_) {                                             \
      DST[m_][0] = *(const bf16x8*)(pa_ + m_ * 2048 + offk0);                    \
      DST[m_][1] = *(const bf16x8*)(pa_ + m_ * 2048 + offk1);                    \
    }                                                                            \
  } while (0)

#define PH_READ_B(DST, BOFF_, NADD) do {                                         \
    const char* pb_ = ldsb + (BOFF_) + 32768 + wn * 8192 + (NADD);               \
    _Pragma("unroll")                                                            \
    for (int n_ = 0; n_ < 2; ++n_) {                                             \
      DST[n_][0] = *(const bf16x8*)(pb_ + n_ * 2048 + offk0);                    \
      DST[n_][1] = *(const bf16x8*)(pb_ + n_ * 2048 + offk1);                    \
    }                                                                            \
  } while (0)

#define MFMA16(AF, BF, MB, NB) do {                                              \
    __builtin_amdgcn_s_setprio(1);                                               \
    _Pragma("unroll")                                                            \
    for (int kk_ = 0; kk_ < 2; ++kk_)                                            \
      _Pragma("unroll")                                                          \
      for (int m_ = 0; m_ < 4; ++m_)                                             \
        _Pragma("unroll")                                                        \
        for (int n_ = 0; n_ < 2; ++n_)                                           \
          acc[(MB) + m_][(NB) + n_] = __builtin_amdgcn_mfma_f32_16x16x32_bf16(   \
              AF[m_][kk_], BF[n_][kk_], acc[(MB) + m_][(NB) + n_], 0, 0, 0);     \
    __builtin_amdgcn_s_setprio(0);                                               \
  } while (0)

// One K-tile: 4 phases, one trailing barrier each.
// DO_ST: stage full tile T+2 at ph3.  VM: 8 = steady vmcnt(8), 0 = drain,
// -1 = none (last tile).
#define TILE(BOFF_, T, DO_ST, VM) do {                                           \
    /* ph0: read A m0-3 + B n0-1; MFMA (m0-3, n0-1) */                           \
    PH_READ_A(af, BOFF_, 0);                                                     \
    PH_READ_B(bfr01, BOFF_, 0);                                                  \
    MFMA16(af, bfr01, 0, 0);                                                     \
    __builtin_amdgcn_s_barrier();                                                \
    /* ph1: read B n2-3; MFMA (m0-3, n2-3) */                                    \
    PH_READ_B(bfr23, BOFF_, 4096);                                               \
    MFMA16(af, bfr23, 0, 2);                                                     \
    __builtin_amdgcn_s_barrier();                                                \
    /* ph2: read A m4-7; MFMA (m4-7, n0-1) */                                    \
    PH_READ_A(af, BOFF_, 8192);                                                  \
    MFMA16(af, bfr01, 4, 0);                                                     \
    __builtin_amdgcn_s_barrier();                                                \
    /* ph3: stage FULL tile T+2 into this buffer; MFMA (m4-7, n2-3) */           \
    if (DO_ST) {                                                                 \
      STAGE_HALF(BOFF_, 0, (T) + 2);                                             \
      STAGE_HALF(BOFF_, 1, (T) + 2);                                             \
      STAGE_HALF(BOFF_, 2, (T) + 2);                                             \
      STAGE_HALF(BOFF_, 3, (T) + 2);                                             \
    }                                                                            \
    MFMA16(af, bfr23, 4, 2);                                                     \
    if ((VM) == 8)      asm volatile("s_waitcnt vmcnt(8)" ::: "memory");         \
    else if ((VM) == 0) asm volatile("s_waitcnt vmcnt(0)" ::: "memory");         \
    if ((VM) >= 0) __builtin_amdgcn_s_barrier();                                 \
  } while (0)

  f32x4 acc[8][4];
#pragma unroll
  for (int i = 0; i < 8; ++i)
#pragma unroll
    for (int j = 0; j < 4; ++j) acc[i][j] = (f32x4)0.0f;

  bf16x8 af[4][2], bfr01[2][2], bfr23[2][2];

  // ---- prologue: stage tiles 0 and 1 fully ----
  STAGE_HALF(0, 0, 0);
  STAGE_HALF(0, 1, 0);
  STAGE_HALF(0, 2, 0);
  STAGE_HALF(0, 3, 0);
  STAGE_HALF(65536, 0, 1);
  STAGE_HALF(65536, 1, 1);
  STAGE_HALF(65536, 2, 1);
  STAGE_HALF(65536, 3, 1);
  asm volatile("s_waitcnt vmcnt(8)" ::: "memory");   // tile 0 resident
  __builtin_amdgcn_s_barrier();

  // ---- main loop: 2 tiles per iteration, tiles 0..61 (all stage t+2) ----
  for (int tp = 0; tp < NKT / 2 - 1; ++tp) {
    const int t0 = 2 * tp;
    TILE(0,     t0,     1, 8);
    TILE(65536, t0 + 1, 1, 8);
  }
  // ---- tail: tile 62 (no stage, drain 63's loads), tile 63 ----
  TILE(0,     NKT - 2, 0, 0);
  TILE(65536, NKT - 1, 0, -1);

#undef TILE
#undef MFMA16
#undef PH_READ_B
#undef PH_READ_A
#undef STAGE_HALF

  // ---- epilogue: bias + relu, fp32 stores ----
  const int c0 = lane & 15;
  const int r0 = (lane >> 4) * 4;
#pragma unroll
  for (int j = 0; j < 4; ++j) {
    const long gc = rowB0 + wn * 64 + j * 16 + c0;
    const float bv = bias[gc];
#pragma unroll
    for (int i = 0; i < 8; ++i) {
      const long gr0 = rowA0 + wm * 128 + i * 16 + r0;
#pragma unroll
      for (int r = 0; r < 4; ++r) {
        float v = acc[i][j][r] + bv;
        Y[(gr0 + r) * (long)N_DIM + gc] = fmaxf(v, 0.0f);
      }
    }
  }
}

// ---------------------------------------------------------------------------
// Fallback (only if ws too small): fp32 reg-staged 128^2 kernel.
// ---------------------------------------------------------------------------
#define FBM 128
#define FBK 32
#define FLDSS 40
__global__ __launch_bounds__(256) void fallback_gemm(
    const float* __restrict__ X, const float* __restrict__ W,
    const float* __restrict__ bias, float* __restrict__ Y) {
  __shared__ short As[FBM * FLDSS];
  __shared__ short Bs[FBM * FLDSS];
  const int tid = threadIdx.x, lane = tid & 63, wave = tid >> 6;
  const int wm = (wave >> 1) * 64, wn = (wave & 1) * 64;
  const long rowA0 = (long)blockIdx.y * FBM, rowB0 = (long)blockIdx.x * FBM;
  const int srow = tid >> 3, scol = (tid & 7) * 4;
  const float* Aptr = X + (rowA0 + srow) * (long)K_DIM + scol;
  const float* Bptr = W + (rowB0 + srow) * (long)K_DIM + scol;
  f32x4 ra[4], rb[4];
#pragma unroll
  for (int i = 0; i < 4; ++i) {
    ra[i] = *(const f32x4*)(Aptr + (long)i * 32 * K_DIM);
    rb[i] = *(const f32x4*)(Bptr + (long)i * 32 * K_DIM);
  }
  f32x4 acc[4][4];
#pragma unroll
  for (int i = 0; i < 4; ++i)
#pragma unroll
    for (int j = 0; j < 4; ++j) acc[i][j] = (f32x4)0.0f;
  for (int kt = 0; kt < K_DIM / FBK; ++kt) {
    __syncthreads();
#pragma unroll
    for (int i = 0; i < 4; ++i) {
      bf16x4v pa, pb;
#pragma unroll
      for (int j = 0; j < 4; ++j) {
        pa[j] = (short)__bfloat16_as_ushort(__float2bfloat16(ra[i][j]));
        pb[j] = (short)__bfloat16_as_ushort(__float2bfloat16(rb[i][j]));
      }
      *(bf16x4v*)&As[(i * 32 + srow) * FLDSS + scol] = pa;
      *(bf16x4v*)&Bs[(i * 32 + srow) * FLDSS + scol] = pb;
    }
    if (kt + 1 < K_DIM / FBK) {
      const float* An = Aptr + (kt + 1) * FBK;
      const float* Bn = Bptr + (kt + 1) * FBK;
#pragma unroll
      for (int i = 0; i < 4; ++i) {
        ra[i] = *(const f32x4*)(An + (long)i * 32 * K_DIM);
        rb[i] = *(const f32x4*)(Bn + (long)i * 32 * K_DIM);
      }
    }
    __syncthreads();
    bf16x8 af[4], bfr[4];
#pragma unroll
    for (int i = 0; i < 4; ++i) {
      af[i]  = *(const bf16x8*)&As[(wm + i * 16 + (lane & 15)) * FLDSS + (lane >> 4) * 8];
      bfr[i] = *(const bf16x8*)&Bs[(wn + i * 16 + (lane & 15)) * FLDSS + (lane >> 4) * 8];
    }
#pragma unroll
    for (int i = 0; i < 4; ++i)
#pragma unroll
      for (int j = 0; j < 4; ++j)
        acc[i][j] = __builtin_amdgcn_mfma_f32_16x16x32_bf16(af[i], bfr[j], acc[i][j], 0, 0, 0);
  }
  const int r0 = (lane >> 4) * 4, c0 = lane & 15;
#pragma unroll
  for (int j = 0; j < 4; ++j) {
    const long gc = rowB0 + wn + j * 16 + c0;
    const float bv = bias[gc];
#pragma unroll
    for (int i = 0; i < 4; ++i) {
      const long gr0 = rowA0 + wm + i * 16 + r0;
#pragma unroll
      for (int r = 0; r < 4; ++r) {
        float v = acc[i][j][r] + bv;
        Y[(gr0 + r) * (long)N_DIM + gc] = fmaxf(v, 0.0f);
      }
    }
  }
}

extern "C" void kernel_launch(void* const* d_in, const int* in_sizes, int n_in,
                              void* d_out, int out_size, void* d_ws, size_t ws_size,
                              hipStream_t stream) {
  const float* x = (const float*)d_in[0];
  const float* w = (const float*)d_in[1];
  const float* b = (const float*)d_in[2];
  float* y = (float*)d_out;

  const size_t need = (size_t)(NX + NW) * sizeof(short);
  if (ws_size >= need) {
    short* ws = (short*)d_ws;
    convert_bf16<<<2048, 256, 0, stream>>>(x, w, ws);
    dim3 grid(N_DIM / BN, M_DIM / BM);
    gemm256_bf16<<<grid, dim3(THREADS), 0, stream>>>(ws, ws + NX, b, y);
  } else {
    dim3 grid(N_DIM / FBM, M_DIM / FBM);
    fallback_gemm<<<grid, dim3(256), 0, stream>>>(x, w, b, y);
  }
}

// Round 9
// 283.899 us; speedup vs baseline: 1.0445x; 1.0445x over previous
//
#include <hip/hip_runtime.h>
#include <hip/hip_bf16.h>

typedef __attribute__((ext_vector_type(4))) float f32x4;
typedef __attribute__((ext_vector_type(16))) float f32x16;
typedef __attribute__((ext_vector_type(8))) short bf16x8;
typedef __attribute__((ext_vector_type(4))) short bf16x4v;

#define M_DIM 8192
#define N_DIM 4096
#define K_DIM 4096
#define NX (M_DIM * K_DIM)
#define NW (N_DIM * K_DIM)

#define BM 256
#define BN 256
#define BK 64
#define NKT (K_DIM / BK)   /* 64 */
#define THREADS 512

#define GLOAD_LDS16(g, l)                                                        \
  __builtin_amdgcn_global_load_lds(                                              \
      (const __attribute__((address_space(1))) void*)(g),                        \
      (__attribute__((address_space(3))) void*)(l), 16, 0, 0)

// ---------------------------------------------------------------------------
// Pass 1: fp32 -> bf16 conversion of x and W into workspace.
// ---------------------------------------------------------------------------
__global__ __launch_bounds__(256) void convert_bf16(const float* __restrict__ x,
                                                    const float* __restrict__ w,
                                                    short* __restrict__ ws) {
  const long stride = (long)gridDim.x * blockDim.x;
  const long total8 = ((long)NX + NW) / 8;
  for (long i = blockIdx.x * (long)blockDim.x + threadIdx.x; i < total8; i += stride) {
    const long base = i * 8;
    const float* src = (base < NX) ? (x + base) : (w + (base - NX));
    short* dst = ws + base;
    f32x4 a = *(const f32x4*)src;
    f32x4 b = *(const f32x4*)(src + 4);
    bf16x8 o;
    o[0] = (short)__bfloat16_as_ushort(__float2bfloat16(a[0]));
    o[1] = (short)__bfloat16_as_ushort(__float2bfloat16(a[1]));
    o[2] = (short)__bfloat16_as_ushort(__float2bfloat16(a[2]));
    o[3] = (short)__bfloat16_as_ushort(__float2bfloat16(a[3]));
    o[4] = (short)__bfloat16_as_ushort(__float2bfloat16(b[0]));
    o[5] = (short)__bfloat16_as_ushort(__float2bfloat16(b[1]));
    o[6] = (short)__bfloat16_as_ushort(__float2bfloat16(b[2]));
    o[7] = (short)__bfloat16_as_ushort(__float2bfloat16(b[3]));
    *(bf16x8*)dst = o;
  }
}

// ---------------------------------------------------------------------------
// Pass 2: 256x256 bf16 GEMM, BK=64, 8 waves (2M x 4N), double-buffered LDS,
// mfma_f32_32x32x16_bf16 (per-wave 4 mt x 2 nt tiles of 32x32, 4 K-slabs).
// 4 phases per K-tile, one trailing barrier each, no lgkm pins; A(t+2)
// staged at ph2, B(t+2) at ph3, single vmcnt(8) gate per tile.
// XOR slot swizzle; XCD-aware block swizzle; setprio.
// Y = relu(X @ W^T + b)
//
// LDS per buffer (64 KiB): A rows 0-255 at [0,32KB), B rows 0-255 at
// [32KB,64KB). Rows 128 B, 8 slots of 16 B, phys slot = logical ^ (row&7).
//
// Operand layouts (32x32x16 bf16):
//  A/B frag: row/col = lane&31, k = (lane>>5)*8 + j  (one b128 per frag)
//  C/D:      col = lane&31, row = (reg&3) + 8*(reg>>2) + 4*(lane>>5)
//
// Race audit:
//  - A reads of tile t: ph0 (mt0-1) + ph1 (mt2-3), consumed same phase ->
//    complete by ph1's trailing barrier -> stage A(t+2) at ph2 is safe.
//  - B reads: ph0 (nt0) + ph2 (nt1), consumed by ph2 -> complete by ph2's
//    trailing barrier -> stage B(t+2) at ph3 is safe.
//  - vmcnt(8) at ph3: outstanding = A(t+2) 4 + B(t+2) 4 younger; waits all
//    older = tile t+1's 8 (issued t-1.ph2/ph3) -> t+1 resident; trailing
//    barrier publishes.  "memory" clobber stops ds_read hoisting.
// ---------------------------------------------------------------------------
__global__ __launch_bounds__(THREADS, 2) void gemm256_bf16(
    const short* __restrict__ Abf,   /* [M][K] bf16 */
    const short* __restrict__ Bbf,   /* [N][K] bf16 */
    const float* __restrict__ bias,
    float* __restrict__ Y) {
  __shared__ short lds[2 * 32768];   /* 128 KiB */
  char* const ldsb = (char*)lds;

  const int tid  = threadIdx.x;
  const int lane = tid & 63;
  const int wave = tid >> 6;       // 0..7
  const int wm   = wave >> 2;      // 0..1  (M half: 128 rows)
  const int wn   = wave & 3;       // 0..3  (N quarter: 64 cols)

  // XCD-aware bijective swizzle: 512 wgs = 8 XCDs x 64.
  const int lin = blockIdx.x + blockIdx.y * (N_DIM / BN);   // gridDim.x = 16
  const int swz = (lin & 7) * 64 + (lin >> 3);
  const int bx = swz & 15;         // N tile
  const int by = swz >> 4;         // M tile
  const long rowA0 = (long)by * BM;
  const long rowB0 = (long)bx * BN;

  // staging: one GLOAD issue = 512 thr x 16 B = 64 rows x 128 B.
  // LDS linear row = wave*8 + (lane>>3) within a 64-row group; phys slot =
  // lane&7; source col chunk = phys ^ (row&7) (inverse swizzle).
  const int sg_col = (((lane & 7) ^ ((lane >> 3) & 7)) << 3);
  const int s_row  = wave * 8 + (lane >> 3);
  const int voff = s_row * K_DIM + sg_col;

  const short* uA = Abf + rowA0 * (long)K_DIM;
  const short* uB = Bbf + rowB0 * (long)K_DIM;

  // fragment-read per-lane byte offsets, one per K-slab s (16 elems):
  // row = tilebase + (lane&31); logical slot = 2*s + (lane>>5);
  // phys = logical ^ (row&7) = logical ^ (lane&7).
  int offs[4];
#pragma unroll
  for (int s = 0; s < 4; ++s)
    offs[s] = (lane & 31) * 128 + ((((2 * s) | (lane >> 5)) ^ (lane & 7)) << 4);

// stage one half-tile (2 gloads). HALF: 0 = A rows 0-127, 1 = A rows 128-255,
// 2 = B rows 0-127, 3 = B rows 128-255.
#define STAGE_HALF(BOFF_, HALF_, TT) do {                                        \
    const short* u_ = ((HALF_) < 2 ? uA : uB) +                                  \
                      (long)(((HALF_) & 1) * 128) * K_DIM + (long)(TT) * BK;     \
    char* l_ = ldsb + (BOFF_) + ((HALF_) < 2 ? 0 : 32768) +                      \
               ((HALF_) & 1) * 16384 + wave * 1024;                              \
    GLOAD_LDS16(u_ + voff, l_);                                                  \
    GLOAD_LDS16(u_ + 64 * K_DIM + voff, l_ + 8192);                              \
  } while (0)

// read 2 A m-tiles (32 rows each) x 4 slabs into DST[2][4]
#define READ_A2(DST, BOFF_, MTB) do {                                            \
    const char* pa_ = ldsb + (BOFF_) + wm * 16384 + (MTB) * 4096;                \
    _Pragma("unroll")                                                            \
    for (int mt_ = 0; mt_ < 2; ++mt_)                                            \
      _Pragma("unroll")                                                          \
      for (int s_ = 0; s_ < 4; ++s_)                                             \
        DST[mt_][s_] = *(const bf16x8*)(pa_ + mt_ * 4096 + offs[s_]);            \
  } while (0)

// read 1 B n-tile (32 cols) x 4 slabs into DST[4]
#define READ_B1(DST, BOFF_, NT) do {                                             \
    const char* pb_ = ldsb + (BOFF_) + 32768 + wn * 8192 + (NT) * 4096;          \
    _Pragma("unroll")                                                            \
    for (int s_ = 0; s_ < 4; ++s_)                                               \
      DST[s_] = *(const bf16x8*)(pb_ + offs[s_]);                                \
  } while (0)

// 8 MFMA (2 mt x 4 slabs) into acc[MT0..MT0+1][NT]
#define MFMA8(AF2, BF, MT0, NT) do {                                             \
    __builtin_amdgcn_s_setprio(1);                                               \
    _Pragma("unroll")                                                            \
    for (int s_ = 0; s_ < 4; ++s_)                                               \
      _Pragma("unroll")                                                          \
      for (int mt_ = 0; mt_ < 2; ++mt_)                                          \
        acc[(MT0) + mt_][NT] = __builtin_amdgcn_mfma_f32_32x32x16_bf16(          \
            AF2[mt_][s_], BF[s_], acc[(MT0) + mt_][NT], 0, 0, 0);                \
    __builtin_amdgcn_s_setprio(0);                                               \
  } while (0)

// One K-tile: 4 phases, one trailing barrier each.
// VM: 8 = steady vmcnt(8), 0 = drain, -1 = none (last tile).
#define TILE(BOFF_, T, DO_ST, VM) do {                                           \
    /* ph0: read A mt0-1 + B nt0; MFMA (mt0-1, nt0) */                           \
    READ_A2(af01, BOFF_, 0);                                                     \
    READ_B1(bf0, BOFF_, 0);                                                      \
    MFMA8(af01, bf0, 0, 0);                                                      \
    __builtin_amdgcn_s_barrier();                                                \
    /* ph1: read A mt2-3; MFMA (mt2-3, nt0) */                                   \
    READ_A2(af23, BOFF_, 2);                                                     \
    MFMA8(af23, bf0, 2, 0);                                                      \
    __builtin_amdgcn_s_barrier();                                                \
    /* ph2: read B nt1; stage A(t+2); MFMA (mt2-3, nt1) */                       \
    READ_B1(bf1, BOFF_, 1);                                                      \
    if (DO_ST) { STAGE_HALF(BOFF_, 0, (T) + 2); STAGE_HALF(BOFF_, 1, (T) + 2); } \
    MFMA8(af23, bf1, 2, 1);                                                      \
    __builtin_amdgcn_s_barrier();                                                \
    /* ph3: stage B(t+2); MFMA (mt0-1, nt1); counted vmcnt gate */               \
    if (DO_ST) { STAGE_HALF(BOFF_, 2, (T) + 2); STAGE_HALF(BOFF_, 3, (T) + 2); } \
    MFMA8(af01, bf1, 0, 1);                                                      \
    if ((VM) == 8)      asm volatile("s_waitcnt vmcnt(8)" ::: "memory");         \
    else if ((VM) == 0) asm volatile("s_waitcnt vmcnt(0)" ::: "memory");         \
    if ((VM) >= 0) __builtin_amdgcn_s_barrier();                                 \
  } while (0)

  f32x16 acc[4][2];
#pragma unroll
  for (int i = 0; i < 4; ++i)
#pragma unroll
    for (int j = 0; j < 2; ++j) acc[i][j] = (f32x16)0.0f;

  bf16x8 af01[2][4], af23[2][4], bf0[4], bf1[4];

  // ---- prologue: stage tiles 0 and 1 fully ----
  STAGE_HALF(0, 0, 0);
  STAGE_HALF(0, 1, 0);
  STAGE_HALF(0, 2, 0);
  STAGE_HALF(0, 3, 0);
  STAGE_HALF(65536, 0, 1);
  STAGE_HALF(65536, 1, 1);
  STAGE_HALF(65536, 2, 1);
  STAGE_HALF(65536, 3, 1);
  asm volatile("s_waitcnt vmcnt(8)" ::: "memory");   // tile 0 resident
  __builtin_amdgcn_s_barrier();

  // ---- main loop: 2 tiles per iteration, tiles 0..61 ----
  for (int tp = 0; tp < NKT / 2 - 1; ++tp) {
    const int t0 = 2 * tp;
    TILE(0,     t0,     1, 8);
    TILE(65536, t0 + 1, 1, 8);
  }
  // ---- tail: tile 62 (no stage, drain 63's loads), tile 63 ----
  TILE(0,     NKT - 2, 0, 0);
  TILE(65536, NKT - 1, 0, -1);

#undef TILE
#undef MFMA8
#undef READ_B1
#undef READ_A2
#undef STAGE_HALF

  // ---- epilogue: bias + relu, fp32 stores ----
  // C/D: col = lane&31, row = (reg&3) + 8*(reg>>2) + 4*(lane>>5)
  const int c0 = lane & 31;
  const int r0 = 4 * (lane >> 5);
#pragma unroll
  for (int nt = 0; nt < 2; ++nt) {
    const long gc = rowB0 + wn * 64 + nt * 32 + c0;
    const float bv = bias[gc];
#pragma unroll
    for (int mt = 0; mt < 4; ++mt) {
      const long gr0 = rowA0 + wm * 128 + mt * 32 + r0;
#pragma unroll
      for (int r = 0; r < 16; ++r) {
        const long gr = gr0 + (r & 3) + 8 * (r >> 2);
        float v = acc[mt][nt][r] + bv;
        Y[gr * (long)N_DIM + gc] = fmaxf(v, 0.0f);
      }
    }
  }
}

// ---------------------------------------------------------------------------
// Fallback (only if ws too small): fp32 reg-staged 128^2 kernel.
// ---------------------------------------------------------------------------
#define FBM 128
#define FBK 32
#define FLDSS 40
__global__ __launch_bounds__(256) void fallback_gemm(
    const float* __restrict__ X, const float* __restrict__ W,
    const float* __restrict__ bias, float* __restrict__ Y) {
  __shared__ short As[FBM * FLDSS];
  __shared__ short Bs[FBM * FLDSS];
  const int tid = threadIdx.x, lane = tid & 63, wave = tid >> 6;
  const int wm = (wave >> 1) * 64, wn = (wave & 1) * 64;
  const long rowA0 = (long)blockIdx.y * FBM, rowB0 = (long)blockIdx.x * FBM;
  const int srow = tid >> 3, scol = (tid & 7) * 4;
  const float* Aptr = X + (rowA0 + srow) * (long)K_DIM + scol;
  const float* Bptr = W + (rowB0 + srow) * (long)K_DIM + scol;
  f32x4 ra[4], rb[4];
#pragma unroll
  for (int i = 0; i < 4; ++i) {
    ra[i] = *(const f32x4*)(Aptr + (long)i * 32 * K_DIM);
    rb[i] = *(const f32x4*)(Bptr + (long)i * 32 * K_DIM);
  }
  f32x4 acc[4][4];
#pragma unroll
  for (int i = 0; i < 4; ++i)
#pragma unroll
    for (int j = 0; j < 4; ++j) acc[i][j] = (f32x4)0.0f;
  for (int kt = 0; kt < K_DIM / FBK; ++kt) {
    __syncthreads();
#pragma unroll
    for (int i = 0; i < 4; ++i) {
      bf16x4v pa, pb;
#pragma unroll
      for (int j = 0; j < 4; ++j) {
        pa[j] = (short)__bfloat16_as_ushort(__float2bfloat16(ra[i][j]));
        pb[j] = (short)__bfloat16_as_ushort(__float2bfloat16(rb[i][j]));
      }
      *(bf16x4v*)&As[(i * 32 + srow) * FLDSS + scol] = pa;
      *(bf16x4v*)&Bs[(i * 32 + srow) * FLDSS + scol] = pb;
    }
    if (kt + 1 < K_DIM / FBK) {
      const float* An = Aptr + (kt + 1) * FBK;
      const float* Bn = Bptr + (kt + 1) * FBK;
#pragma unroll
      for (int i = 0; i < 4; ++i) {
        ra[i] = *(const f32x4*)(An + (long)i * 32 * K_DIM);
        rb[i] = *(const f32x4*)(Bn + (long)i * 32 * K_DIM);
      }
    }
    __syncthreads();
    bf16x8 af[4], bfr[4];
#pragma unroll
    for (int i = 0; i < 4; ++i) {
      af[i]  = *(const bf16x8*)&As[(wm + i * 16 + (lane & 15)) * FLDSS + (lane >> 4) * 8];
      bfr[i] = *(const bf16x8*)&Bs[(wn + i * 16 + (lane & 15)) * FLDSS + (lane >> 4) * 8];
    }
#pragma unroll
    for (int i = 0; i < 4; ++i)
#pragma unroll
      for (int j = 0; j < 4; ++j)
        acc[i][j] = __builtin_amdgcn_mfma_f32_16x16x32_bf16(af[i], bfr[j], acc[i][j], 0, 0, 0);
  }
  const int r0 = (lane >> 4) * 4, c0 = lane & 15;
#pragma unroll
  for (int j = 0; j < 4; ++j) {
    const long gc = rowB0 + wn + j * 16 + c0;
    const float bv = bias[gc];
#pragma unroll
    for (int i = 0; i < 4; ++i) {
      const long gr0 = rowA0 + wm + i * 16 + r0;
#pragma unroll
      for (int r = 0; r < 4; ++r) {
        float v = acc[i][j][r] + bv;
        Y[(gr0 + r) * (long)N_DIM + gc] = fmaxf(v, 0.0f);
      }
    }
  }
}

extern "C" void kernel_launch(void* const* d_in, const int* in_sizes, int n_in,
                              void* d_out, int out_size, void* d_ws, size_t ws_size,
                              hipStream_t stream) {
  const float* x = (const float*)d_in[0];
  const float* w = (const float*)d_in[1];
  const float* b = (const float*)d_in[2];
  float* y = (float*)d_out;

  const size_t need = (size_t)(NX + NW) * sizeof(short);
  if (ws_size >= need) {
    short* ws = (short*)d_ws;
    convert_bf16<<<2048, 256, 0, stream>>>(x, w, ws);
    dim3 grid(N_DIM / BN, M_DIM / BM);
    gemm256_bf16<<<grid, dim3(THREADS), 0, stream>>>(ws, ws + NX, b, y);
  } else {
    dim3 grid(N_DIM / FBM, M_DIM / FBM);
    fallback_gemm<<<grid, dim3(256), 0, stream>>>(x, w, b, y);
  }
}

// Round 10
// 251.290 us; speedup vs baseline: 1.1801x; 1.1298x over previous
//
#include <hip/hip_runtime.h>
#include <hip/hip_bf16.h>

typedef __attribute__((ext_vector_type(4))) float f32x4;
typedef __attribute__((ext_vector_type(8))) short bf16x8;
typedef __attribute__((ext_vector_type(4))) short bf16x4v;

#define M_DIM 8192
#define N_DIM 4096
#define K_DIM 4096
#define NX (M_DIM * K_DIM)
#define NW (N_DIM * K_DIM)

#define BM 256
#define BN 256
#define BK 64
#define NKT (K_DIM / BK)   /* 64 */
#define THREADS 512

#define GLOAD_LDS16(g, l)                                                        \
  __builtin_amdgcn_global_load_lds(                                              \
      (const __attribute__((address_space(1))) void*)(g),                        \
      (__attribute__((address_space(3))) void*)(l), 16, 0, 0)

// ---------------------------------------------------------------------------
// Pass 1: fp32 -> bf16 conversion of x and W into workspace.
// ---------------------------------------------------------------------------
__global__ __launch_bounds__(256) void convert_bf16(const float* __restrict__ x,
                                                    const float* __restrict__ w,
                                                    short* __restrict__ ws) {
  const long stride = (long)gridDim.x * blockDim.x;
  const long total8 = ((long)NX + NW) / 8;
  for (long i = blockIdx.x * (long)blockDim.x + threadIdx.x; i < total8; i += stride) {
    const long base = i * 8;
    const float* src = (base < NX) ? (x + base) : (w + (base - NX));
    short* dst = ws + base;
    f32x4 a = *(const f32x4*)src;
    f32x4 b = *(const f32x4*)(src + 4);
    bf16x8 o;
    o[0] = (short)__bfloat16_as_ushort(__float2bfloat16(a[0]));
    o[1] = (short)__bfloat16_as_ushort(__float2bfloat16(a[1]));
    o[2] = (short)__bfloat16_as_ushort(__float2bfloat16(a[2]));
    o[3] = (short)__bfloat16_as_ushort(__float2bfloat16(a[3]));
    o[4] = (short)__bfloat16_as_ushort(__float2bfloat16(b[0]));
    o[5] = (short)__bfloat16_as_ushort(__float2bfloat16(b[1]));
    o[6] = (short)__bfloat16_as_ushort(__float2bfloat16(b[2]));
    o[7] = (short)__bfloat16_as_ushort(__float2bfloat16(b[3]));
    *(bf16x8*)dst = o;
  }
}

// ---------------------------------------------------------------------------
// Pass 2: 256x256 bf16 GEMM, BK=64, 8 waves (2M x 4N), double-buffered LDS,
// 4 phases per K-tile, one trailing barrier each, no lgkm pins (compiler
// emits fine-grained lgkmcnt).  Staging of tile t+2: B halves at ph2
// (B reads sealed by ph1's barrier), A halves at ph3 (A sealed by ph2's
// barrier) -> every load has ~2 K-tiles of flight before its vmcnt(8) gate,
// issue spread 4+4 per tile (no burst).  XOR slot swizzle; XCD swizzle;
// setprio.  Coalesced epilogue via per-wave LDS transpose.
// Y = relu(X @ W^T + b)
//
// LDS per buffer (64 KiB): A rows 0-255 at [0,32KB) (half0 rows 0-127,
// half1 rows 128-255), B likewise at [32KB,64KB). Rows 128 B, 8 slots of
// 16 B, phys slot = logical ^ (row&7).
//
// Race audit:
//  - B reads of tile t (rows wn*64..+63, all in buf[t&1] B region) are
//    consumed by ph0/ph1 MFMAs -> complete before ph1's trailing barrier
//    -> stage B(t+2) at ph2 is safe.
//  - A reads: ph0 (m0-3) + ph2 (m4-7, consumed by ph2 MFMA) -> sealed by
//    ph2's trailing barrier -> stage A(t+2) at ph3 is safe.
//  - vmcnt(8) at ph3: outstanding = B(t+2) 4 + A(t+2) 4 newest; waits all
//    older = tile t+1's 8 -> t+1 resident; trailing barrier publishes.
//  - Epilogue LDS scratch uses buf0 only; every wave passed tile 62's
//    trailing barrier (VM=0 drain) and tile 63 touches only buf1 -> buf0
//    is dead, per-wave-private regions, no extra barrier needed.
// ---------------------------------------------------------------------------
__global__ __launch_bounds__(THREADS, 2) void gemm256_bf16(
    const short* __restrict__ Abf,   /* [M][K] bf16 */
    const short* __restrict__ Bbf,   /* [N][K] bf16 */
    const float* __restrict__ bias,
    float* __restrict__ Y) {
  __shared__ short lds[2 * 32768];   /* 128 KiB */
  char* const ldsb = (char*)lds;

  const int tid  = threadIdx.x;
  const int lane = tid & 63;
  const int wave = tid >> 6;       // 0..7
  const int wm   = wave >> 2;      // 0..1  (M half)
  const int wn   = wave & 3;       // 0..3  (N quarter)

  // XCD-aware bijective swizzle: 512 wgs = 8 XCDs x 64.
  const int lin = blockIdx.x + blockIdx.y * (N_DIM / BN);   // gridDim.x = 16
  const int swz = (lin & 7) * 64 + (lin >> 3);
  const int bx = swz & 15;         // N tile
  const int by = swz >> 4;         // M tile
  const long rowA0 = (long)by * BM;
  const long rowB0 = (long)bx * BN;

  // staging: one GLOAD issue = 512 thr x 16 B = 64 rows x 128 B.
  // LDS linear row = wave*8 + (lane>>3) within a 64-row group; phys slot =
  // lane&7; source col chunk = phys ^ (row&7) (inverse swizzle).
  const int sg_col = (((lane & 7) ^ ((lane >> 3) & 7)) << 3);
  const int s_row  = wave * 8 + (lane >> 3);
  const int voff = s_row * K_DIM + sg_col;

  const short* uA = Abf + rowA0 * (long)K_DIM;
  const short* uB = Bbf + rowB0 * (long)K_DIM;

  // fragment-read per-lane byte offsets: row = frag*16 + (lane&15),
  // phys slot = kslot ^ (row&7) = kslot ^ (lane&7).
  const int offk0 = (lane & 15) * 128 + ((((lane >> 4)) ^ (lane & 7)) << 4);
  const int offk1 = (lane & 15) * 128 + (((4 + (lane >> 4)) ^ (lane & 7)) << 4);

// stage one half-tile (2 gloads). HALF: 0 = A rows 0-127, 1 = A rows 128-255,
// 2 = B rows 0-127, 3 = B rows 128-255.
#define STAGE_HALF(BOFF_, HALF_, TT) do {                                        \
    const short* u_ = ((HALF_) < 2 ? uA : uB) +                                  \
                      (long)(((HALF_) & 1) * 128) * K_DIM + (long)(TT) * BK;     \
    char* l_ = ldsb + (BOFF_) + ((HALF_) < 2 ? 0 : 32768) +                      \
               ((HALF_) & 1) * 16384 + wave * 1024;                              \
    GLOAD_LDS16(u_ + voff, l_);                                                  \
    GLOAD_LDS16(u_ + 64 * K_DIM + voff, l_ + 8192);                              \
  } while (0)

#define PH_READ_A(DST, BOFF_, MADD) do {                                         \
    const char* pa_ = ldsb + (BOFF_) + wm * 16384 + (MADD);                      \
    _Pragma("unroll")                                                            \
    for (int m_ = 0; m_ < 4; ++m_) {                                             \
      DST[m_][0] = *(const bf16x8*)(pa_ + m_ * 2048 + offk0);                    \
      DST[m_][1] = *(const bf16x8*)(pa_ + m_ * 2048 + offk1);                    \
    }                                                                            \
  } while (0)

#define PH_READ_B(DST, BOFF_, NADD) do {                                         \
    const char* pb_ = ldsb + (BOFF_) + 32768 + wn * 8192 + (NADD);               \
    _Pragma("unroll")                                                            \
    for (int n_ = 0; n_ < 2; ++n_) {                                             \
      DST[n_][0] = *(const bf16x8*)(pb_ + n_ * 2048 + offk0);                    \
      DST[n_][1] = *(const bf16x8*)(pb_ + n_ * 2048 + offk1);                    \
    }                                                                            \
  } while (0)

#define MFMA16(AF, BF, MB, NB) do {                                              \
    __builtin_amdgcn_s_setprio(1);                                               \
    _Pragma("unroll")                                                            \
    for (int kk_ = 0; kk_ < 2; ++kk_)                                            \
      _Pragma("unroll")                                                          \
      for (int m_ = 0; m_ < 4; ++m_)                                             \
        _Pragma("unroll")                                                        \
        for (int n_ = 0; n_ < 2; ++n_)                                           \
          acc[(MB) + m_][(NB) + n_] = __builtin_amdgcn_mfma_f32_16x16x32_bf16(   \
              AF[m_][kk_], BF[n_][kk_], acc[(MB) + m_][(NB) + n_], 0, 0, 0);     \
    __builtin_amdgcn_s_setprio(0);                                               \
  } while (0)

// One K-tile: 4 phases, one trailing barrier each.
// VM: 8 = steady vmcnt(8), 0 = drain, -1 = none (last tile).
#define TILE(BOFF_, T, DO_ST, VM) do {                                           \
    /* ph0: read A m0-3 + B n0-1; MFMA (m0-3, n0-1) */                           \
    PH_READ_A(af, BOFF_, 0);                                                     \
    PH_READ_B(bfr01, BOFF_, 0);                                                  \
    MFMA16(af, bfr01, 0, 0);                                                     \
    __builtin_amdgcn_s_barrier();                                                \
    /* ph1: read B n2-3; MFMA (m0-3, n2-3) */                                    \
    PH_READ_B(bfr23, BOFF_, 4096);                                               \
    MFMA16(af, bfr23, 0, 2);                                                     \
    __builtin_amdgcn_s_barrier();                                                \
    /* ph2: read A m4-7; stage B(T+2); MFMA (m4-7, n0-1) */                      \
    PH_READ_A(af, BOFF_, 8192);                                                  \
    if (DO_ST) { STAGE_HALF(BOFF_, 2, (T) + 2); STAGE_HALF(BOFF_, 3, (T) + 2); } \
    MFMA16(af, bfr01, 4, 0);                                                     \
    __builtin_amdgcn_s_barrier();                                                \
    /* ph3: stage A(T+2); MFMA (m4-7, n2-3); counted vmcnt gate */               \
    if (DO_ST) { STAGE_HALF(BOFF_, 0, (T) + 2); STAGE_HALF(BOFF_, 1, (T) + 2); } \
    MFMA16(af, bfr23, 4, 2);                                                     \
    if ((VM) == 8)      asm volatile("s_waitcnt vmcnt(8)" ::: "memory");         \
    else if ((VM) == 0) asm volatile("s_waitcnt vmcnt(0)" ::: "memory");         \
    if ((VM) >= 0) __builtin_amdgcn_s_barrier();                                 \
  } while (0)

  f32x4 acc[8][4];
#pragma unroll
  for (int i = 0; i < 8; ++i)
#pragma unroll
    for (int j = 0; j < 4; ++j) acc[i][j] = (f32x4)0.0f;

  bf16x8 af[4][2], bfr01[2][2], bfr23[2][2];

  // ---- prologue: stage tiles 0 and 1 fully ----
  STAGE_HALF(0, 0, 0);
  STAGE_HALF(0, 1, 0);
  STAGE_HALF(0, 2, 0);
  STAGE_HALF(0, 3, 0);
  STAGE_HALF(65536, 2, 1);
  STAGE_HALF(65536, 3, 1);
  STAGE_HALF(65536, 0, 1);
  STAGE_HALF(65536, 1, 1);
  asm volatile("s_waitcnt vmcnt(8)" ::: "memory");   // tile 0 resident
  __builtin_amdgcn_s_barrier();

  // ---- main loop: 2 tiles per iteration, tiles 0..61 ----
  for (int tp = 0; tp < NKT / 2 - 1; ++tp) {
    const int t0 = 2 * tp;
    TILE(0,     t0,     1, 8);
    TILE(65536, t0 + 1, 1, 8);
  }
  // ---- tail: tile 62 (no stage, drain 63's loads), tile 63 ----
  TILE(0,     NKT - 2, 0, 0);
  TILE(65536, NKT - 1, 0, -1);

#undef TILE
#undef MFMA16
#undef PH_READ_B
#undef PH_READ_A
#undef STAGE_HALF

  // ---- epilogue: per-wave LDS transpose -> 128-B-segment f32x4 stores ----
  // Scratch: buf0 (dead), per-wave 8 KB region; 16 rows x 32 cols fp32 per
  // round, padded row stride 144 B (bank-spread for b128 reads).
  {
    char* scr = ldsb + wave * 8192;
    const int c0 = lane & 15;
    const int r0 = (lane >> 4) * 4;
    const int rd_row = lane >> 3;        // 0..7
    const int rd_ch  = (lane & 7) * 16;  // 16-B chunk within 128-B row
#pragma unroll
    for (int jp = 0; jp < 2; ++jp) {
      const long gcb = rowB0 + wn * 64 + jp * 32 + (lane & 7) * 4;
      const f32x4 bv4 = *(const f32x4*)&bias[gcb];
#pragma unroll
      for (int i = 0; i < 8; ++i) {
        // write phase: this lane's 8 values of frags (i, 2jp) and (i, 2jp+1)
#pragma unroll
        for (int r = 0; r < 4; ++r) {
          *(float*)(scr + (r0 + r) * 144 + c0 * 4)      = acc[i][2 * jp + 0][r];
          *(float*)(scr + (r0 + r) * 144 + 64 + c0 * 4) = acc[i][2 * jp + 1][r];
        }
        // read phase: full 128-B rows (8 lanes/row), rows rd_row and rd_row+8
        f32x4 v0 = *(const f32x4*)(scr + rd_row * 144 + rd_ch);
        f32x4 v1 = *(const f32x4*)(scr + (8 + rd_row) * 144 + rd_ch);
        v0 += bv4;
        v1 += bv4;
#pragma unroll
        for (int e = 0; e < 4; ++e) {
          v0[e] = fmaxf(v0[e], 0.0f);
          v1[e] = fmaxf(v1[e], 0.0f);
        }
        const long gr = rowA0 + wm * 128 + i * 16;
        *(f32x4*)&Y[(gr + rd_row) * (long)N_DIM + gcb]     = v0;
        *(f32x4*)&Y[(gr + 8 + rd_row) * (long)N_DIM + gcb] = v1;
      }
    }
  }
}

// ---------------------------------------------------------------------------
// Fallback (only if ws too small): fp32 reg-staged 128^2 kernel.
// ---------------------------------------------------------------------------
#define FBM 128
#define FBK 32
#define FLDSS 40
__global__ __launch_bounds__(256) void fallback_gemm(
    const float* __restrict__ X, const float* __restrict__ W,
    const float* __restrict__ bias, float* __restrict__ Y) {
  __shared__ short As[FBM * FLDSS];
  __shared__ short Bs[FBM * FLDSS];
  const int tid = threadIdx.x, lane = tid & 63, wave = tid >> 6;
  const int wm = (wave >> 1) * 64, wn = (wave & 1) * 64;
  const long rowA0 = (long)blockIdx.y * FBM, rowB0 = (long)blockIdx.x * FBM;
  const int srow = tid >> 3, scol = (tid & 7) * 4;
  const float* Aptr = X + (rowA0 + srow) * (long)K_DIM + scol;
  const float* Bptr = W + (rowB0 + srow) * (long)K_DIM + scol;
  f32x4 ra[4], rb[4];
#pragma unroll
  for (int i = 0; i < 4; ++i) {
    ra[i] = *(const f32x4*)(Aptr + (long)i * 32 * K_DIM);
    rb[i] = *(const f32x4*)(Bptr + (long)i * 32 * K_DIM);
  }
  f32x4 acc[4][4];
#pragma unroll
  for (int i = 0; i < 4; ++i)
#pragma unroll
    for (int j = 0; j < 4; ++j) acc[i][j] = (f32x4)0.0f;
  for (int kt = 0; kt < K_DIM / FBK; ++kt) {
    __syncthreads();
#pragma unroll
    for (int i = 0; i < 4; ++i) {
      bf16x4v pa, pb;
#pragma unroll
      for (int j = 0; j < 4; ++j) {
        pa[j] = (short)__bfloat16_as_ushort(__float2bfloat16(ra[i][j]));
        pb[j] = (short)__bfloat16_as_ushort(__float2bfloat16(rb[i][j]));
      }
      *(bf16x4v*)&As[(i * 32 + srow) * FLDSS + scol] = pa;
      *(bf16x4v*)&Bs[(i * 32 + srow) * FLDSS + scol] = pb;
    }
    if (kt + 1 < K_DIM / FBK) {
      const float* An = Aptr + (kt + 1) * FBK;
      const float* Bn = Bptr + (kt + 1) * FBK;
#pragma unroll
      for (int i = 0; i < 4; ++i) {
        ra[i] = *(const f32x4*)(An + (long)i * 32 * K_DIM);
        rb[i] = *(const f32x4*)(Bn + (long)i * 32 * K_DIM);
      }
    }
    __syncthreads();
    bf16x8 af[4], bfr[4];
#pragma unroll
    for (int i = 0; i < 4; ++i) {
      af[i]  = *(const bf16x8*)&As[(wm + i * 16 + (lane & 15)) * FLDSS + (lane >> 4) * 8];
      bfr[i] = *(const bf16x8*)&Bs[(wn + i * 16 + (lane & 15)) * FLDSS + (lane >> 4) * 8];
    }
#pragma unroll
    for (int i = 0; i < 4; ++i)
#pragma unroll
      for (int j = 0; j < 4; ++j)
        acc[i][j] = __builtin_amdgcn_mfma_f32_16x16x32_bf16(af[i], bfr[j], acc[i][j], 0, 0, 0);
  }
  const int r0 = (lane >> 4) * 4, c0 = lane & 15;
#pragma unroll
  for (int j = 0; j < 4; ++j) {
    const long gc = rowB0 + wn + j * 16 + c0;
    const float bv = bias[gc];
#pragma unroll
    for (int i = 0; i < 4; ++i) {
      const long gr0 = rowA0 + wm + i * 16 + r0;
#pragma unroll
      for (int r = 0; r < 4; ++r) {
        float v = acc[i][j][r] + bv;
        Y[(gr0 + r) * (long)N_DIM + gc] = fmaxf(v, 0.0f);
      }
    }
  }
}

extern "C" void kernel_launch(void* const* d_in, const int* in_sizes, int n_in,
                              void* d_out, int out_size, void* d_ws, size_t ws_size,
                              hipStream_t stream) {
  const float* x = (const float*)d_in[0];
  const float* w = (const float*)d_in[1];
  const float* b = (const float*)d_in[2];
  float* y = (float*)d_out;

  const size_t need = (size_t)(NX + NW) * sizeof(short);
  if (ws_size >= need) {
    short* ws = (short*)d_ws;
    convert_bf16<<<2048, 256, 0, stream>>>(x, w, ws);
    dim3 grid(N_DIM / BN, M_DIM / BM);
    gemm256_bf16<<<grid, dim3(THREADS), 0, stream>>>(ws, ws + NX, b, y);
  } else {
    dim3 grid(N_DIM / FBM, M_DIM / FBM);
    fallback_gemm<<<grid, dim3(256), 0, stream>>>(x, w, b, y);
  }
}